// Round 2
// baseline (1594.801 us; speedup 1.0000x reference)
//
#include <hip/hip_runtime.h>
#include <cstdint>
#include <cstddef>

#define GLOBAL_AS __attribute__((address_space(1)))
#define LDS_AS    __attribute__((address_space(3)))

typedef __bf16 bf16;
typedef __bf16 bf16x8 __attribute__((ext_vector_type(8)));
typedef float  f32x4  __attribute__((ext_vector_type(4)));

__device__ __forceinline__ void gl_lds16(const void* g, void* l) {
  // 16B-per-lane async global->LDS; LDS dest = wave-uniform base + lane*16
  __builtin_amdgcn_global_load_lds((GLOBAL_AS void*)g, (LDS_AS void*)l, 16, 0, 0);
}

// ---------------- LayerNorm: fp32 (rows of 2048) -> bf16 ----------------
__global__ __launch_bounds__(256) void ln_kernel(const float* __restrict__ x,
                                                 const float* __restrict__ w,
                                                 const float* __restrict__ bias,
                                                 bf16* __restrict__ out) {
  const int row = blockIdx.x;
  const int tid = threadIdx.x;
  const float* xr = x + (size_t)row * 2048;
  f32x4 v0 = ((const f32x4*)xr)[tid * 2];
  f32x4 v1 = ((const f32x4*)xr)[tid * 2 + 1];
  float s = 0.f, ss = 0.f;
#pragma unroll
  for (int j = 0; j < 4; ++j) { s += v0[j]; ss += v0[j] * v0[j]; }
#pragma unroll
  for (int j = 0; j < 4; ++j) { s += v1[j]; ss += v1[j] * v1[j]; }
#pragma unroll
  for (int d = 1; d < 64; d <<= 1) { s += __shfl_xor(s, d); ss += __shfl_xor(ss, d); }
  __shared__ float red[8];
  const int wave = tid >> 6, lane = tid & 63;
  if (lane == 0) { red[wave * 2] = s; red[wave * 2 + 1] = ss; }
  __syncthreads();
  s  = red[0] + red[2] + red[4] + red[6];
  ss = red[1] + red[3] + red[5] + red[7];
  const float mean = s * (1.f / 2048.f);
  const float var  = ss * (1.f / 2048.f) - mean * mean;  // biased, matches jnp var
  const float rstd = rsqrtf(var + 1e-5f);
  const int col = tid * 8;
  bf16x8 o;
#pragma unroll
  for (int j = 0; j < 4; ++j) o[j]     = (bf16)((v0[j] - mean) * rstd * w[col + j]     + bias[col + j]);
#pragma unroll
  for (int j = 0; j < 4; ++j) o[4 + j] = (bf16)((v1[j] - mean) * rstd * w[col + 4 + j] + bias[col + 4 + j]);
  *(bf16x8*)(out + (size_t)row * 2048 + col) = o;
}

// -------- Dequant + LoRA fold: W[o,i] = qw*sc[o]+zp[o]+2*(B@A)[o,i] --------
__global__ __launch_bounds__(256) void dequant_kernel(const int* __restrict__ qw,
    const float* __restrict__ sc, const float* __restrict__ zp,
    const float* __restrict__ A, const float* __restrict__ Bm,
    bf16* __restrict__ W, int out_f, int in_f) {
  const int per_row = in_f >> 3;
  const int idx = blockIdx.x * 256 + threadIdx.x;   // grid sized exactly out_f*in_f/8/256
  const int o  = idx / per_row;
  const int i0 = (idx - o * per_row) << 3;
  const float s = sc[o], z = zp[o];
  float bl[16];
#pragma unroll
  for (int r = 0; r < 16; ++r) bl[r] = Bm[o * 16 + r];
  float acc[8] = {0.f, 0.f, 0.f, 0.f, 0.f, 0.f, 0.f, 0.f};
#pragma unroll
  for (int r = 0; r < 16; ++r) {
    const f32x4* ap = (const f32x4*)(A + (size_t)r * in_f + i0);
    f32x4 a0 = ap[0], a1 = ap[1];
#pragma unroll
    for (int j = 0; j < 4; ++j) { acc[j] += bl[r] * a0[j]; acc[4 + j] += bl[r] * a1[j]; }
  }
  const int* qp = qw + (size_t)o * in_f + i0;
  bf16x8 w8;
#pragma unroll
  for (int j = 0; j < 8; ++j) w8[j] = (bf16)((float)qp[j] * s + z + 2.f * acc[j]);
  *(bf16x8*)(W + (size_t)o * in_f + i0) = w8;
}

// -------- bf16 GEMM: C[M,N] = A[M,K] @ B[N,K]^T (both K-contiguous), 128x128 tile, BK=64 --------
// MODE 0: Cb = bf16(acc).
// MODE 1: Cf = res + acc (fp32 residual add; res may alias Cf).
// MODE 2: Cb = silu(gate)*acc, in-place safe when gate==Cb.
template <int MODE>
__global__ __launch_bounds__(256) void gemm_kernel(const bf16* __restrict__ A,
    const bf16* __restrict__ B, bf16* __restrict__ Cb, float* __restrict__ Cf,
    const float* __restrict__ res, const bf16* __restrict__ gate,
    int M, int N, int K) {
  const int n0 = blockIdx.x * 128;
  const int m0 = blockIdx.y * 128;
  const int tid = threadIdx.x;
  const int wave = tid >> 6, lane = tid & 63;
  const int lcol = lane & 15, lrow = lane >> 4;
  const int wm = (wave >> 1) * 64, wn = (wave & 1) * 64;
  __shared__ bf16 As[128 * 64];
  __shared__ bf16 Bs[128 * 64];
  f32x4 acc[4][4] = {};
  // staging: wave w covers tile rows [32w,32w+32), 8 rows per instr (128B/row)
  const bf16* Ag = A + (size_t)(m0 + wave * 32 + (lane >> 3)) * K + (lane & 7) * 8;
  const bf16* Bg = B + (size_t)(n0 + wave * 32 + (lane >> 3)) * K + (lane & 7) * 8;
  for (int kt = 0; kt < K; kt += 64) {
#pragma unroll
    for (int r8 = 0; r8 < 4; ++r8) {
      gl_lds16(Ag + (size_t)r8 * 8 * K + kt, As + (wave * 32 + r8 * 8) * 64);
      gl_lds16(Bg + (size_t)r8 * 8 * K + kt, Bs + (wave * 32 + r8 * 8) * 64);
    }
    __syncthreads();
#pragma unroll
    for (int ks = 0; ks < 2; ++ks) {
      bf16x8 af[4], bfr[4];
#pragma unroll
      for (int i = 0; i < 4; ++i) af[i]  = *(const bf16x8*)(As + (wm + i * 16 + lcol) * 64 + ks * 32 + lrow * 8);
#pragma unroll
      for (int j = 0; j < 4; ++j) bfr[j] = *(const bf16x8*)(Bs + (wn + j * 16 + lcol) * 64 + ks * 32 + lrow * 8);
#pragma unroll
      for (int i = 0; i < 4; ++i)
#pragma unroll
        for (int j = 0; j < 4; ++j)
          acc[i][j] = __builtin_amdgcn_mfma_f32_16x16x32_bf16(af[i], bfr[j], acc[i][j], 0, 0, 0);
    }
    __syncthreads();
  }
#pragma unroll
  for (int i = 0; i < 4; ++i)
#pragma unroll
    for (int j = 0; j < 4; ++j)
#pragma unroll
      for (int r = 0; r < 4; ++r) {
        const int row = m0 + wm + i * 16 + lrow * 4 + r;   // C/D: row = quad*4+reg
        const int col = n0 + wn + j * 16 + lcol;           //      col = lane&15
        const size_t idx = (size_t)row * N + col;
        if (MODE == 0) {
          Cb[idx] = (bf16)acc[i][j][r];
        } else if (MODE == 1) {
          Cf[idx] = res[idx] + acc[i][j][r];
        } else {
          const float g = (float)gate[idx];
          Cb[idx] = (bf16)((g / (1.f + __expf(-g))) * acc[i][j][r]);
        }
      }
}

// -------- Flash attention: qkv packed [4096][6144] (q|k|v each h*128+d), full softmax --------
__global__ __launch_bounds__(256) void attn_kernel(const bf16* __restrict__ qkv,
                                                   bf16* __restrict__ obuf) {
  const int qt = blockIdx.x, h = blockIdx.y, b = blockIdx.z;
  const int tid = threadIdx.x, wave = tid >> 6, lane = tid & 63;
  const int lcol = lane & 15, lrow = lane >> 4;
  const int base_m = b * 2048 + qt * 128;
  __shared__ bf16 Ks[64 * 128];      // [s][d]
  __shared__ bf16 Vt[128 * 72];      // [d][s], stride 72 (144B, 16B-aligned rows)
  __shared__ bf16 Ps[4][32 * 72];    // per-wave P, stride 72
  // Q fragments in registers (wave's 32 q-rows, A-operand layout)
  bf16x8 qf[2][4];
#pragma unroll
  for (int i = 0; i < 2; ++i)
#pragma unroll
    for (int dk = 0; dk < 4; ++dk)
      qf[i][dk] = *(const bf16x8*)(qkv + (size_t)(base_m + wave * 32 + i * 16 + lcol) * 6144
                                   + h * 128 + dk * 32 + lrow * 8);
  f32x4 of[2][8] = {};
  float m_run[2][4], l_run[2][4];
#pragma unroll
  for (int i = 0; i < 2; ++i)
#pragma unroll
    for (int r = 0; r < 4; ++r) { m_run[i][r] = -1e30f; l_run[i][r] = 0.f; }
  const float SC = 0.08838834764831845f;  // 1/sqrt(128)

  for (int kt = 0; kt < 2048; kt += 64) {
    // stage K tile (async, 4 rows per instr per wave)
#pragma unroll
    for (int rr = 0; rr < 4; ++rr)
      gl_lds16(qkv + (size_t)(b * 2048 + kt + wave * 16 + rr * 4 + lrow) * 6144 + 2048 + h * 128 + lcol * 8,
               Ks + (wave * 16 + rr * 4) * 128);
    // stage V transposed (manual, padded stride)
    {
      const int s = lane;
#pragma unroll
      for (int dblk = 0; dblk < 4; ++dblk) {
        const int d0 = wave * 8 + dblk * 32;
        bf16x8 vv = *(const bf16x8*)(qkv + (size_t)(b * 2048 + kt + s) * 6144 + 4096 + h * 128 + d0);
#pragma unroll
        for (int jj = 0; jj < 8; ++jj) Vt[(d0 + jj) * 72 + s] = vv[jj];
      }
    }
    __syncthreads();

    // S = Q @ K^T
    f32x4 sacc[2][4] = {};
#pragma unroll
    for (int jb = 0; jb < 4; ++jb) {
      bf16x8 kf[4];
#pragma unroll
      for (int dk = 0; dk < 4; ++dk) kf[dk] = *(const bf16x8*)(Ks + (jb * 16 + lcol) * 128 + dk * 32 + lrow * 8);
#pragma unroll
      for (int i = 0; i < 2; ++i)
#pragma unroll
        for (int dk = 0; dk < 4; ++dk)
          sacc[i][jb] = __builtin_amdgcn_mfma_f32_16x16x32_bf16(qf[i][dk], kf[dk], sacc[i][jb], 0, 0, 0);
    }

    // online softmax per 16-row block; row r lives in quad (lane>>4), reduce over lanes 0..15
#pragma unroll
    for (int i = 0; i < 2; ++i) {
      float z[4][4];
#pragma unroll
      for (int jb = 0; jb < 4; ++jb)
#pragma unroll
        for (int r = 0; r < 4; ++r) z[jb][r] = sacc[i][jb][r] * SC;
      float mx[4], rs[4];
#pragma unroll
      for (int r = 0; r < 4; ++r)
        mx[r] = fmaxf(fmaxf(z[0][r], z[1][r]), fmaxf(z[2][r], z[3][r]));
#pragma unroll
      for (int d = 1; d < 16; d <<= 1)
#pragma unroll
        for (int r = 0; r < 4; ++r) mx[r] = fmaxf(mx[r], __shfl_xor(mx[r], d));
#pragma unroll
      for (int r = 0; r < 4; ++r) {
        const float mn = fmaxf(m_run[i][r], mx[r]);
        const float alpha = __expf(m_run[i][r] - mn);
        m_run[i][r] = mn;
        float srow = 0.f;
#pragma unroll
        for (int jb = 0; jb < 4; ++jb) { float p = __expf(z[jb][r] - mn); z[jb][r] = p; srow += p; }
        rs[r] = srow;
        l_run[i][r] *= alpha;
#pragma unroll
        for (int db = 0; db < 8; ++db) of[i][db][r] *= alpha;
      }
#pragma unroll
      for (int d = 1; d < 16; d <<= 1)
#pragma unroll
        for (int r = 0; r < 4; ++r) rs[r] += __shfl_xor(rs[r], d);
#pragma unroll
      for (int r = 0; r < 4; ++r) l_run[i][r] += rs[r];
      // P: C-layout regs -> LDS (bf16) so PV can read A-layout
#pragma unroll
      for (int jb = 0; jb < 4; ++jb)
#pragma unroll
        for (int r = 0; r < 4; ++r)
          Ps[wave][(i * 16 + lrow * 4 + r) * 72 + jb * 16 + lcol] = (bf16)z[jb][r];
    }

    // O += P @ V
#pragma unroll
    for (int ss = 0; ss < 2; ++ss) {
      bf16x8 a0 = *(const bf16x8*)(&Ps[wave][(0 * 16 + lcol) * 72 + ss * 32 + lrow * 8]);
      bf16x8 a1 = *(const bf16x8*)(&Ps[wave][(1 * 16 + lcol) * 72 + ss * 32 + lrow * 8]);
#pragma unroll
      for (int db = 0; db < 8; ++db) {
        bf16x8 vf = *(const bf16x8*)(Vt + (db * 16 + lcol) * 72 + ss * 32 + lrow * 8);
        of[0][db] = __builtin_amdgcn_mfma_f32_16x16x32_bf16(a0, vf, of[0][db], 0, 0, 0);
        of[1][db] = __builtin_amdgcn_mfma_f32_16x16x32_bf16(a1, vf, of[1][db], 0, 0, 0);
      }
    }
    __syncthreads();
  }
#pragma unroll
  for (int i = 0; i < 2; ++i)
#pragma unroll
    for (int db = 0; db < 8; ++db)
#pragma unroll
      for (int r = 0; r < 4; ++r) {
        const int row = base_m + wave * 32 + i * 16 + lrow * 4 + r;
        const int col = h * 128 + db * 16 + lcol;
        obuf[(size_t)row * 2048 + col] = (bf16)(of[i][db][r] / l_run[i][r]);
      }
}

extern "C" void kernel_launch(void* const* d_in, const int* in_sizes, int n_in,
                              void* d_out, int out_size, void* d_ws, size_t ws_size,
                              hipStream_t stream) {
  (void)in_sizes; (void)n_in; (void)out_size; (void)ws_size;
  // input order = setup_inputs() dict order
  const int*   q_qw = (const int*)d_in[0];   const float* q_sc = (const float*)d_in[1];
  const float* q_zp = (const float*)d_in[2]; const float* q_A  = (const float*)d_in[3];
  const float* q_B  = (const float*)d_in[4];
  const int*   k_qw = (const int*)d_in[5];   const float* k_sc = (const float*)d_in[6];
  const float* k_zp = (const float*)d_in[7]; const float* k_A  = (const float*)d_in[8];
  const float* k_B  = (const float*)d_in[9];
  const int*   v_qw = (const int*)d_in[10];  const float* v_sc = (const float*)d_in[11];
  const float* v_zp = (const float*)d_in[12];const float* v_A  = (const float*)d_in[13];
  const float* v_B  = (const float*)d_in[14];
  const int*   o_qw = (const int*)d_in[15];  const float* o_sc = (const float*)d_in[16];
  const float* o_zp = (const float*)d_in[17];const float* o_A  = (const float*)d_in[18];
  const float* o_B  = (const float*)d_in[19];
  const int*   g_qw = (const int*)d_in[20];  const float* g_sc = (const float*)d_in[21];
  const float* g_zp = (const float*)d_in[22];const float* g_A  = (const float*)d_in[23];
  const float* g_B  = (const float*)d_in[24];
  const int*   u_qw = (const int*)d_in[25];  const float* u_sc = (const float*)d_in[26];
  const float* u_zp = (const float*)d_in[27];const float* u_A  = (const float*)d_in[28];
  const float* u_B  = (const float*)d_in[29];
  const int*   d_qw = (const int*)d_in[30];  const float* d_sc = (const float*)d_in[31];
  const float* d_zp = (const float*)d_in[32];const float* d_A  = (const float*)d_in[33];
  const float* d_B  = (const float*)d_in[34];
  const float* x    = (const float*)d_in[35];
  const float* ln1w = (const float*)d_in[36];const float* ln1b = (const float*)d_in[37];
  const float* ln2w = (const float*)d_in[38];const float* ln2b = (const float*)d_in[39];

  // workspace arena — peak 112 MiB (W 32 + h 16 + C 64); x1 lives in d_out (fp32)
  char* ws = (char*)d_ws;
  bf16* W = (bf16*)ws;                                    // 32 MiB: dequant scratch (all layers)
  bf16* h = (bf16*)(ws + (size_t)32 * 1024 * 1024);       // 16 MiB: LN1 out, then LN2 out
  bf16* C = (bf16*)(ws + (size_t)48 * 1024 * 1024);       // 64 MiB: Cqkv(48)+obuf(16), then Cg/ff(64)
  bf16* Cqkv = C;
  bf16* obuf = C + (size_t)4096 * 6144;                   // +48 MiB
  float* x1  = (float*)d_out;                             // residual stream 1 (fp32, in-place final)
  float* out = (float*)d_out;

  // 1. h = LN1(x)
  ln_kernel<<<4096, 256, 0, stream>>>(x, ln1w, ln1b, h);
  // 2. dequant W_q|W_k|W_v (concat rows -> 6144x2048, 24 MiB)
  dequant_kernel<<<2048, 256, 0, stream>>>(q_qw, q_sc, q_zp, q_A, q_B, W, 2048, 2048);
  dequant_kernel<<<2048, 256, 0, stream>>>(k_qw, k_sc, k_zp, k_A, k_B, W + (size_t)2048 * 2048, 2048, 2048);
  dequant_kernel<<<2048, 256, 0, stream>>>(v_qw, v_sc, v_zp, v_A, v_B, W + (size_t)4096 * 2048, 2048, 2048);
  // 3. qkv = h @ W^T
  gemm_kernel<0><<<dim3(48, 32), 256, 0, stream>>>(h, W, Cqkv, nullptr, nullptr, nullptr, 4096, 6144, 2048);
  // 4. attention
  attn_kernel<<<dim3(16, 16, 2), 256, 0, stream>>>(Cqkv, obuf);
  // 5-6. x1 = x + o @ W_o^T  (x1 in d_out)
  dequant_kernel<<<2048, 256, 0, stream>>>(o_qw, o_sc, o_zp, o_A, o_B, W, 2048, 2048);
  gemm_kernel<1><<<dim3(16, 32), 256, 0, stream>>>(obuf, W, nullptr, x1, x, nullptr, 4096, 2048, 2048);
  // 7. h2 = LN2(x1)
  ln_kernel<<<4096, 256, 0, stream>>>(x1, ln2w, ln2b, h);
  // 8-9. g = h2 @ W_g^T   (Cg = C, 64 MiB; Cqkv/obuf dead)
  dequant_kernel<<<8192, 256, 0, stream>>>(g_qw, g_sc, g_zp, g_A, g_B, W, 8192, 2048);
  gemm_kernel<0><<<dim3(64, 32), 256, 0, stream>>>(h, W, C, nullptr, nullptr, nullptr, 4096, 8192, 2048);
  // 10-11. ff = silu(g) * (h2 @ W_u^T), fused epilogue, in-place over C
  dequant_kernel<<<8192, 256, 0, stream>>>(u_qw, u_sc, u_zp, u_A, u_B, W, 8192, 2048);
  gemm_kernel<2><<<dim3(64, 32), 256, 0, stream>>>(h, W, C, nullptr, nullptr, C, 4096, 8192, 2048);
  // 12-13. out = x1 + ff @ W_d^T  (in-place over d_out)
  dequant_kernel<<<8192, 256, 0, stream>>>(d_qw, d_sc, d_zp, d_A, d_B, W, 2048, 8192);
  gemm_kernel<1><<<dim3(16, 32), 256, 0, stream>>>(C, W, nullptr, out, x1, nullptr, 4096, 2048, 8192);
}